// Round 13
// baseline (161.512 us; speedup 1.0000x reference)
//
#include <hip/hip_runtime.h>
#include <hip/hip_bf16.h>

#define NN 16384
#define DD 256

typedef unsigned short u16;
typedef unsigned int u32;
typedef unsigned char u8;
typedef long i64;
typedef __attribute__((ext_vector_type(4))) float f32x4;
typedef __attribute__((ext_vector_type(4))) int i32x4;
typedef __attribute__((ext_vector_type(8))) int i32x8;

// ---------- kernel 1: fp8 e4m3 convert, LDS-transposed, all-coalesced ----------
// (verbatim from R6 -- measured clean, absmax 0.)
// A8 and B8 share ONE fragment-linear layout:
//   addr = pn<<15 | k2<<14 | r8<<11 | jj<<10 | qq<<8 | mm<<4 | u
//   holding fp8 of row (pn*128 + r8*16 + mm), kbyte (k2*128 + qq*32 + jj*16 + u).
__global__ __launch_bounds__(256) void prep_kernel(
        const float* __restrict__ img, const float* __restrict__ txt,
        u8* __restrict__ A8, u8* __restrict__ B8,
        float* __restrict__ zbuf /* s_row..s_col 32768 f */,
        float* __restrict__ out) {
    __shared__ u32 sA[16 * 65 + 8];
    __shared__ u32 sB[16 * 65 + 8];
    const int t = threadIdx.x, bi = blockIdx.x;            // bi = 16-row window
    const float4* ib = (const float4*)img + ((size_t)bi << 10);
    const float4* tb = (const float4*)txt + ((size_t)bi << 10);
    const float S = 1.44269504088896f;                     // log2(e) folded into A
    #pragma unroll
    for (int k = 0; k < 4; ++k) {
        const int idx = (k << 8) + t;                      // 0..1023 float4s
        const int row = idx >> 6, col = idx & 63;          // row 0..15, col 0..63
        float4 va = ib[idx];
        int pa = __builtin_amdgcn_cvt_pk_fp8_f32(va.x * S, va.y * S, 0, false);
        pa     = __builtin_amdgcn_cvt_pk_fp8_f32(va.z * S, va.w * S, pa, true);
        sA[row * 65 + col] = (u32)pa;
        float4 vb = tb[idx];
        int pb = __builtin_amdgcn_cvt_pk_fp8_f32(vb.x, vb.y, 0, false);
        pb     = __builtin_amdgcn_cvt_pk_fp8_f32(vb.z, vb.w, pb, true);
        sB[row * 65 + col] = (u32)pb;
    }
    __syncthreads();
    const int w = t >> 6, l = t & 63;
    const int k2 = w >> 1, jj = w & 1, qq = l >> 4, mm = l & 15;
    const int wb = mm * 65 + (k2 << 5) + (qq << 3) + (jj << 2);
    i32x4 oa = { (int)sA[wb], (int)sA[wb + 1], (int)sA[wb + 2], (int)sA[wb + 3] };
    i32x4 ob = { (int)sB[wb], (int)sB[wb + 1], (int)sB[wb + 2], (int)sB[wb + 3] };
    const size_t dst = ((size_t)(bi >> 3) << 15) + (k2 << 14) + ((size_t)(bi & 7) << 11)
                     + (jj << 10) + (qq << 8) + (mm << 4);
    *(i32x4*)(A8 + dst) = oa;
    *(i32x4*)(B8 + dst) = ob;
    const int gid = (bi << 8) + t;
    if (gid < 32768) zbuf[gid] = 0.0f;
    if (gid == 0) out[0] = 0.0f;
}

// ---------- kernel 2: MX-scaled fp8 GEMM + exp2 + row/col sum ----------
// vs R11 (78.5 us, MfmaUtil 37.7, VALUBusy 46): FORCED MFMA||VALU INTERLEAVE.
// R11 showed load latency is NOT binding (rotation = R8). MFMA pipe busy 2.2k
// + VALU busy 2.7k ~ wall 5.9k cyc/tile => pipes SERIALIZED: in-order waves
// can't issue epilogue VALU during their MFMA cluster, and the 2 same-phase
// waves/SIMD want the same pipe simultaneously. Fix (one mechanism, 3 edits):
// (1) steady loop = single BB: jt=0/15 peeled, diag MOVED to final_kernel
//     (recomputed from the same quantized A8/B8 bytes -> branch-free epilogue);
// (2) sched_group_barrier emission template {VMEM_READ 1, MFMA 2, VALU 6,
//     TRANS 4} x16 per iteration: 2 MFMAs (~69 cyc pipe) alternate with ~10
//     epilogue VALU/exp2 ops -> epilogue(bank X) executes inside the MFMA
//     shadows of bank Y (no deps: MFMAs write the other bank);
// (3) rotating one-frag prefetch kept (neutral, zero cost).
// Spill tripwire: WRITE_SIZE 17.47 MB / FETCH 18.5 MB / VGPR <= ~130.
__global__ __launch_bounds__(256, 2) void gemm_lse_kernel(
        const u8* __restrict__ A8, const u8* __restrict__ B8,
        float* __restrict__ s_row, float* __restrict__ s_col) {
    const int t = threadIdx.x;
    const int lane = t & 63;
    const int w = t >> 6;
    const int wr = w >> 1, wc = w & 1;
    const int q = lane >> 4, m = lane & 15;
    const int bi = blockIdx.x & 127;
    const int jg = blockIdx.x >> 7;
    const int row0 = bi << 7;

    // ---- A fragments direct from global (fragment-linear, coalesced) ----
    const u8* Aw = A8 + ((size_t)bi << 15) + ((size_t)lane << 4);
    i32x8 areg[2][4];
    #pragma unroll
    for (int k2 = 0; k2 < 2; ++k2)
        #pragma unroll
        for (int rb = 0; rb < 4; ++rb) {
            const u8* p = Aw + (k2 << 14) + (((wr << 2) + rb) << 11);
            i32x4 lo = *(const i32x4*)(p);
            i32x4 hi = *(const i32x4*)(p + 1024);
            areg[k2][rb] = __builtin_shufflevector(lo, hi, 0, 1, 2, 3, 4, 5, 6, 7);
        }

    const f32x4 fzero = {0.f, 0.f, 0.f, 0.f};
    f32x4 accA[4][2], accB[4][2];                 // half-tile acc banks (static)
    f32x4 rp[4] = {fzero, fzero, fzero, fzero};   // row partials
    float cpartT = 0.0f;                          // per-tile col partial

    const u8* Bw = B8 + (wc << 13) + ((size_t)lane << 4);

    i32x8 bf0, bf1, bf2, bf3;   // rotating one-fragment banks (slot i&3)

    // load fragment for slot ii (ii in 0..7: h=ii>>2, k2=(ii>>1)&1, cbl=ii&1)
    auto load_slot = [&](i32x8& bank, int jt_, int ii) {
        const int ct = (jg << 4) | ((jt_ + bi) & 15);
        const u8* pp = Bw + ((size_t)ct << 15) + ((ii >> 2) << 12)
                     + (((ii >> 1) & 1) << 14) + ((ii & 1) << 11);
        i32x4 lo = *(const i32x4*)(pp);
        i32x4 hi = *(const i32x4*)(pp + 1024);
        bank = __builtin_shufflevector(lo, hi, 0, 1, 2, 3, 4, 5, 6, 7);
    };

    // 4 MFMAs of one slot (k2_, cbl_ are call-site literals -> static acc idx)
    auto mfma_slot = [&](f32x4 (&acc)[4][2], const i32x8& bank, int k2_, int cbl_) {
        const f32x4 cinit = {-144.f, -144.f, -144.f, -144.f}; // exp2 bias in C
        if (k2_ == 0) {
            #pragma unroll
            for (int rb = 0; rb < 4; ++rb)
                acc[rb][cbl_] = __builtin_amdgcn_mfma_scale_f32_16x16x128_f8f6f4(
                    areg[0][rb], bank, cinit, 0, 0, 0, 127, 0, 127);
        } else {
            #pragma unroll
            for (int rb = 0; rb < 4; ++rb)
                acc[rb][cbl_] = __builtin_amdgcn_mfma_scale_f32_16x16x128_f8f6f4(
                    areg[1][rb], bank, acc[rb][cbl_], 0, 0, 0, 127, 0, 127);
        }
    };

    // epilogue for a finished half: exp2, row/col partials (branch-free)
    auto epilogue_half = [&](f32x4 (&acc)[4][2], int jt_, int h) {
        const int ct = (jg << 4) | ((jt_ + bi) & 15);
        #pragma unroll
        for (int rb = 0; rb < 4; ++rb)
            #pragma unroll
            for (int cb = 0; cb < 2; ++cb)
                #pragma unroll
                for (int r = 0; r < 4; ++r)
                    acc[rb][cb][r] = __builtin_amdgcn_exp2f(acc[rb][cb][r]);
        #pragma unroll
        for (int rb = 0; rb < 4; ++rb)
            rp[rb] += acc[rb][0] + acc[rb][1];
        #pragma unroll
        for (int cb = 0; cb < 2; ++cb) {
            f32x4 s = (acc[0][cb] + acc[1][cb]) + (acc[2][cb] + acc[3][cb]);
            float v = (s[0] + s[1]) + (s[2] + s[3]);
            v += __shfl_xor(v, 16, 64);
            v += __shfl_xor(v, 32, 64);
            if (q == ((h << 1) | cb)) cpartT = v;
        }
        if (h == 1) {   // h is a call-site literal -> compile-time
            const int col0 = ct << 7;
            atomicAdd(&s_col[col0 + (wc << 6) + (q << 4) + m], cpartT);
        }
    };

    // ---- peeled jt = 0 (no previous epilogue) ----
    load_slot(bf0, 0, 0);
    load_slot(bf1, 0, 1);
    load_slot(bf2, 0, 2);  mfma_slot(accA, bf0, 0, 0);
    load_slot(bf3, 0, 3);  mfma_slot(accA, bf1, 0, 1);
    load_slot(bf0, 0, 4);  mfma_slot(accA, bf2, 1, 0);
    load_slot(bf1, 0, 5);  mfma_slot(accA, bf3, 1, 1);
    load_slot(bf2, 0, 6);  mfma_slot(accB, bf0, 0, 0);
    load_slot(bf3, 0, 7);  mfma_slot(accB, bf1, 0, 1);
    load_slot(bf0, 1, 0);  mfma_slot(accB, bf2, 1, 0);
    load_slot(bf1, 1, 1);  mfma_slot(accB, bf3, 1, 1);
    epilogue_half(accA, 0, 0);

    // ---- steady loop jt = 1..14: single BB + SGB emission template ----
    #pragma unroll 1
    for (int jt = 1; jt < 15; ++jt) {
        load_slot(bf2, jt, 2);  mfma_slot(accA, bf0, 0, 0);
        load_slot(bf3, jt, 3);  mfma_slot(accA, bf1, 0, 1);
        load_slot(bf0, jt, 4);  mfma_slot(accA, bf2, 1, 0);
        load_slot(bf1, jt, 5);  mfma_slot(accA, bf3, 1, 1);
        epilogue_half(accB, jt - 1, 1);
        load_slot(bf2, jt, 6);  mfma_slot(accB, bf0, 0, 0);
        load_slot(bf3, jt, 7);  mfma_slot(accB, bf1, 0, 1);
        load_slot(bf0, jt + 1, 0);  mfma_slot(accB, bf2, 1, 0);
        load_slot(bf1, jt + 1, 1);  mfma_slot(accB, bf3, 1, 1);
        epilogue_half(accA, jt, 0);
        // emission template: {VMEM_READ 1, MFMA 2, VALU 6, TRANS 4} x 16
        // (16 VMEM, 32 MFMA, 96 VALU, 64 TRANS per iteration; soft groups)
        #pragma unroll
        for (int g = 0; g < 16; ++g) {
            __builtin_amdgcn_sched_group_barrier(0x020, 1, 0);  // VMEM_READ
            __builtin_amdgcn_sched_group_barrier(0x008, 2, 0);  // MFMA
            __builtin_amdgcn_sched_group_barrier(0x002, 6, 0);  // VALU
            __builtin_amdgcn_sched_group_barrier(0x400, 4, 0);  // TRANS
        }
    }

    // ---- peeled jt = 15 (no next-tile loads) ----
    load_slot(bf2, 15, 2);  mfma_slot(accA, bf0, 0, 0);
    load_slot(bf3, 15, 3);  mfma_slot(accA, bf1, 0, 1);
    load_slot(bf0, 15, 4);  mfma_slot(accA, bf2, 1, 0);
    load_slot(bf1, 15, 5);  mfma_slot(accA, bf3, 1, 1);
    epilogue_half(accB, 14, 1);
    load_slot(bf2, 15, 6);  mfma_slot(accB, bf0, 0, 0);
    load_slot(bf3, 15, 7);  mfma_slot(accB, bf1, 0, 1);
    mfma_slot(accB, bf2, 1, 0);
    mfma_slot(accB, bf3, 1, 1);
    epilogue_half(accA, 15, 0);
    epilogue_half(accB, 15, 1);

    // ---- block-end row reduction ----
    float rout = 0.0f;
    #pragma unroll
    for (int rb = 0; rb < 4; ++rb)
        #pragma unroll
        for (int r = 0; r < 4; ++r) {
            float v = rp[rb][r];
            v += __shfl_xor(v, 1, 16);
            v += __shfl_xor(v, 2, 16);
            v += __shfl_xor(v, 4, 16);
            v += __shfl_xor(v, 8, 16);
            if (m == ((rb << 2) | r)) rout = v;
        }
    atomicAdd(&s_row[row0 + (wr << 6) + ((m >> 2) << 4) + (q << 2) + (m & 3)], rout);
}

// ---------- kernel 3: final reduce (64 blocks, 256 rows each) ----------
// diag recomputed HERE from the same quantized A8/B8 bytes (row dot via
// cvt_f32_fp8 with LITERAL byte selectors -- R12's loop-var selector was a
// frontend error). dot = x_ii*log2e, matches the GEMM diagonal up to
// summation order (~1e-6 rel). p = 0.5*(log2 sr + log2 sc) + 144 - dot.
__global__ void final_kernel(const u8* __restrict__ A8, const u8* __restrict__ B8,
                             const float* __restrict__ s_row, const float* __restrict__ s_col,
                             float* __restrict__ out) {
    __shared__ double red[256];
    int t = threadIdx.x;
    int i = blockIdx.x * 256 + t;
    const int pn = i >> 7, r8 = (i >> 4) & 7, mm = i & 15;
    const u8* pa = A8 + ((size_t)pn << 15) + (r8 << 11) + (mm << 4);
    const u8* pb = B8 + ((size_t)pn << 15) + (r8 << 11) + (mm << 4);
    float dot = 0.0f;
    #pragma unroll
    for (int k2 = 0; k2 < 2; ++k2)
        #pragma unroll
        for (int jj = 0; jj < 2; ++jj)
            #pragma unroll
            for (int qq = 0; qq < 4; ++qq) {
                const int off = (k2 << 14) + (jj << 10) + (qq << 8);
                i32x4 wa = *(const i32x4*)(pa + off);
                i32x4 wb = *(const i32x4*)(pb + off);
                #pragma unroll
                for (int d = 0; d < 4; ++d) {
                    dot += __builtin_amdgcn_cvt_f32_fp8(wa[d], 0)
                         * __builtin_amdgcn_cvt_f32_fp8(wb[d], 0);
                    dot += __builtin_amdgcn_cvt_f32_fp8(wa[d], 1)
                         * __builtin_amdgcn_cvt_f32_fp8(wb[d], 1);
                    dot += __builtin_amdgcn_cvt_f32_fp8(wa[d], 2)
                         * __builtin_amdgcn_cvt_f32_fp8(wb[d], 2);
                    dot += __builtin_amdgcn_cvt_f32_fp8(wa[d], 3)
                         * __builtin_amdgcn_cvt_f32_fp8(wb[d], 3);
                }
            }
    double p = 0.5 * (double)(log2f(s_row[i]) + log2f(s_col[i])) + 144.0 - (double)dot;
    red[t] = p;
    __syncthreads();
    for (int s = 128; s > 0; s >>= 1) {
        if (t < s) red[t] += red[t + s];
        __syncthreads();
    }
    if (t == 0) atomicAdd(out, (float)(red[0] * 0.6931471805599453 / (double)NN));
}

// ---------- launch ----------
extern "C" void kernel_launch(void* const* d_in, const int* in_sizes, int n_in,
                              void* d_out, int out_size, void* d_ws, size_t ws_size,
                              hipStream_t stream) {
    const float* img = (const float*)d_in[0];
    const float* txt = (const float*)d_in[1];
    char* ws = (char*)d_ws;
    u8*    A8    = (u8*)ws;                                // 4 MB
    u8*    B8    = (u8*)(ws + 4194304);                    // 4 MB
    float* s_row = (float*)(ws + 8388608);                 // 64 KB
    float* s_col = (float*)(ws + 8388608 + 65536);         // 64 KB
    float* out   = (float*)d_out;

    prep_kernel<<<1024, 256, 0, stream>>>(img, txt, A8, B8, s_row, out);
    gemm_lse_kernel<<<1024, 256, 0, stream>>>(A8, B8, s_row, s_col);
    final_kernel<<<64, 256, 0, stream>>>(A8, B8, s_row, s_col, out);
}

// Round 14
// 143.847 us; speedup vs baseline: 1.1228x; 1.1228x over previous
//
#include <hip/hip_runtime.h>
#include <hip/hip_bf16.h>

#define NN 16384
#define DD 256

typedef unsigned short u16;
typedef unsigned int u32;
typedef unsigned char u8;
typedef long i64;
typedef __attribute__((ext_vector_type(4))) float f32x4;
typedef __attribute__((ext_vector_type(4))) int i32x4;
typedef __attribute__((ext_vector_type(8))) int i32x8;

// ---------- kernel 1: fp8 e4m3 convert, LDS-transposed, all-coalesced ----------
// (verbatim from R6 -- measured clean, absmax 0.)
// A8 and B8 share ONE fragment-linear layout:
//   addr = pn<<15 | k2<<14 | r8<<11 | jj<<10 | qq<<8 | mm<<4 | u
//   holding fp8 of row (pn*128 + r8*16 + mm), kbyte (k2*128 + qq*32 + jj*16 + u).
__global__ __launch_bounds__(256) void prep_kernel(
        const float* __restrict__ img, const float* __restrict__ txt,
        u8* __restrict__ A8, u8* __restrict__ B8,
        float* __restrict__ zbuf /* s_row..s_col 32768 f */,
        float* __restrict__ out) {
    __shared__ u32 sA[16 * 65 + 8];
    __shared__ u32 sB[16 * 65 + 8];
    const int t = threadIdx.x, bi = blockIdx.x;            // bi = 16-row window
    const float4* ib = (const float4*)img + ((size_t)bi << 10);
    const float4* tb = (const float4*)txt + ((size_t)bi << 10);
    const float S = 1.44269504088896f;                     // log2(e) folded into A
    #pragma unroll
    for (int k = 0; k < 4; ++k) {
        const int idx = (k << 8) + t;                      // 0..1023 float4s
        const int row = idx >> 6, col = idx & 63;          // row 0..15, col 0..63
        float4 va = ib[idx];
        int pa = __builtin_amdgcn_cvt_pk_fp8_f32(va.x * S, va.y * S, 0, false);
        pa     = __builtin_amdgcn_cvt_pk_fp8_f32(va.z * S, va.w * S, pa, true);
        sA[row * 65 + col] = (u32)pa;
        float4 vb = tb[idx];
        int pb = __builtin_amdgcn_cvt_pk_fp8_f32(vb.x, vb.y, 0, false);
        pb     = __builtin_amdgcn_cvt_pk_fp8_f32(vb.z, vb.w, pb, true);
        sB[row * 65 + col] = (u32)pb;
    }
    __syncthreads();
    const int w = t >> 6, l = t & 63;
    const int k2 = w >> 1, jj = w & 1, qq = l >> 4, mm = l & 15;
    const int wb = mm * 65 + (k2 << 5) + (qq << 3) + (jj << 2);
    i32x4 oa = { (int)sA[wb], (int)sA[wb + 1], (int)sA[wb + 2], (int)sA[wb + 3] };
    i32x4 ob = { (int)sB[wb], (int)sB[wb + 1], (int)sB[wb + 2], (int)sB[wb + 3] };
    const size_t dst = ((size_t)(bi >> 3) << 15) + (k2 << 14) + ((size_t)(bi & 7) << 11)
                     + (jj << 10) + (qq << 8) + (mm << 4);
    *(i32x4*)(A8 + dst) = oa;
    *(i32x4*)(B8 + dst) = ob;
    const int gid = (bi << 8) + t;
    if (gid < 32768) zbuf[gid] = 0.0f;
    if (gid == 0) out[0] = 0.0f;
}

// ---------- kernel 2: MX-scaled fp8 GEMM + exp2 + row/col sum + diag ----------
// EXACT R11 (best measured: gemm 78.5 us, clean counters) + ONE edit:
// ANTI-PHASE SKEW. R13's compile-time interleave (SGB template) regressed
// (78.5 -> 89.9): pinning emission order beats the scheduler. Runtime fix
// instead: the 2 resident waves/SIMD (one per co-resident block, pair
// (b, b+256)) start together, run identical code, and stay PHASE-LOCKED --
// both want the MFMA pipe, then both want VALU (wall 5.9k = 2.2k MFMA +
// 2.7k VALU + 1k stall, serialized). m114: an MFMA-wave and a VALU-wave
// co-schedule fully (time = max). So skew one block of each pair by half a
// tile-phase (~2.9k cyc, s_sleep 3x960) -> block A's MFMA cluster overlaps
// block B's epilogue permanently (no barriers to re-lock). Predicate
// (blockIdx.x>>8)&1 because co-resident pairs differ in bit 8.
// Tripwires (pure-delay edit, must not move): VGPR ~108, WRITE 17.47 MB,
// FETCH 18.5 MB, conflicts 0.
__global__ __launch_bounds__(256, 2) void gemm_lse_kernel(
        const u8* __restrict__ A8, const u8* __restrict__ B8,
        float* __restrict__ s_row, float* __restrict__ s_col,
        float* __restrict__ diag) {
    // ---- anti-phase skew: half a tile-phase for one block of each pair ----
    if ((blockIdx.x >> 8) & 1) {
        __builtin_amdgcn_s_sleep(15);   // 960 cyc
        __builtin_amdgcn_s_sleep(15);   // 960 cyc
        __builtin_amdgcn_s_sleep(15);   // 960 cyc  (~2.9k total)
    }

    const int t = threadIdx.x;
    const int lane = t & 63;
    const int w = t >> 6;
    const int wr = w >> 1, wc = w & 1;
    const int q = lane >> 4, m = lane & 15;
    const int bi = blockIdx.x & 127;
    const int jg = blockIdx.x >> 7;
    const int row0 = bi << 7;

    // ---- A fragments direct from global (fragment-linear, coalesced) ----
    const u8* Aw = A8 + ((size_t)bi << 15) + ((size_t)lane << 4);
    i32x8 areg[2][4];
    #pragma unroll
    for (int k2 = 0; k2 < 2; ++k2)
        #pragma unroll
        for (int rb = 0; rb < 4; ++rb) {
            const u8* p = Aw + (k2 << 14) + (((wr << 2) + rb) << 11);
            i32x4 lo = *(const i32x4*)(p);
            i32x4 hi = *(const i32x4*)(p + 1024);
            areg[k2][rb] = __builtin_shufflevector(lo, hi, 0, 1, 2, 3, 4, 5, 6, 7);
        }

    const f32x4 fzero = {0.f, 0.f, 0.f, 0.f};
    f32x4 accA[4][2], accB[4][2];                 // half-tile acc banks (static)
    f32x4 rp[4] = {fzero, fzero, fzero, fzero};   // row partials
    float cpartT = 0.0f;                          // per-tile col partial

    const u8* Bw = B8 + (wc << 13) + ((size_t)lane << 4);

    i32x8 bf0, bf1, bf2, bf3;   // rotating one-fragment banks (slot i&3)

    // load fragment for slot ii (ii in 0..7: h=ii>>2, k2=(ii>>1)&1, cbl=ii&1)
    auto load_slot = [&](i32x8& bank, int jt_, int ii) {
        const int ct = (jg << 4) | ((jt_ + bi) & 15);
        const u8* pp = Bw + ((size_t)ct << 15) + ((ii >> 2) << 12)
                     + (((ii >> 1) & 1) << 14) + ((ii & 1) << 11);
        i32x4 lo = *(const i32x4*)(pp);
        i32x4 hi = *(const i32x4*)(pp + 1024);
        bank = __builtin_shufflevector(lo, hi, 0, 1, 2, 3, 4, 5, 6, 7);
    };

    // 4 MFMAs of one slot (k2_, cbl_ are call-site literals -> static acc idx)
    auto mfma_slot = [&](f32x4 (&acc)[4][2], const i32x8& bank, int k2_, int cbl_) {
        const f32x4 cinit = {-144.f, -144.f, -144.f, -144.f}; // exp2 bias in C
        if (k2_ == 0) {
            #pragma unroll
            for (int rb = 0; rb < 4; ++rb)
                acc[rb][cbl_] = __builtin_amdgcn_mfma_scale_f32_16x16x128_f8f6f4(
                    areg[0][rb], bank, cinit, 0, 0, 0, 127, 0, 127);
        } else {
            #pragma unroll
            for (int rb = 0; rb < 4; ++rb)
                acc[rb][cbl_] = __builtin_amdgcn_mfma_scale_f32_16x16x128_f8f6f4(
                    areg[1][rb], bank, acc[rb][cbl_], 0, 0, 0, 127, 0, 127);
        }
    };

    // epilogue for a finished half (diag, exp2, row/col partials)
    auto epilogue_half = [&](f32x4 (&acc)[4][2], int jt_, int h) {
        const int ct = (jg << 4) | ((jt_ + bi) & 15);
        if (bi == ct && wr == wc) {
            #pragma unroll
            for (int rb = 0; rb < 4; ++rb)
                if ((rb >> 1) == h) {
                    #pragma unroll
                    for (int r = 0; r < 4; ++r)
                        if (m == ((q << 2) | r))
                            diag[row0 + (wr << 6) + (rb << 4) + m] = acc[rb][rb & 1][r];
                }
        }
        #pragma unroll
        for (int rb = 0; rb < 4; ++rb)
            #pragma unroll
            for (int cb = 0; cb < 2; ++cb)
                #pragma unroll
                for (int r = 0; r < 4; ++r)
                    acc[rb][cb][r] = __builtin_amdgcn_exp2f(acc[rb][cb][r]);
        #pragma unroll
        for (int rb = 0; rb < 4; ++rb)
            rp[rb] += acc[rb][0] + acc[rb][1];
        #pragma unroll
        for (int cb = 0; cb < 2; ++cb) {
            f32x4 s = (acc[0][cb] + acc[1][cb]) + (acc[2][cb] + acc[3][cb]);
            float v = (s[0] + s[1]) + (s[2] + s[3]);
            v += __shfl_xor(v, 16, 64);
            v += __shfl_xor(v, 32, 64);
            if (q == ((h << 1) | cb)) cpartT = v;
        }
        if (h == 1) {
            const int col0 = ct << 7;
            atomicAdd(&s_col[col0 + (wc << 6) + (q << 4) + m], cpartT);
        }
    };

    // ---- rotating-prefetch main loop: load slot s+2 at slot s ----
    load_slot(bf0, 0, 0);
    load_slot(bf1, 0, 1);
    #pragma unroll 1
    for (int jt = 0; jt < 16; ++jt) {
        load_slot(bf2, jt, 2);  mfma_slot(accA, bf0, 0, 0);   // slot 0
        load_slot(bf3, jt, 3);  mfma_slot(accA, bf1, 0, 1);   // slot 1
        load_slot(bf0, jt, 4);  mfma_slot(accA, bf2, 1, 0);   // slot 2
        load_slot(bf1, jt, 5);  mfma_slot(accA, bf3, 1, 1);   // slot 3
        if (jt > 0) epilogue_half(accB, jt - 1, 1);
        load_slot(bf2, jt, 6);  mfma_slot(accB, bf0, 0, 0);   // slot 4
        load_slot(bf3, jt, 7);  mfma_slot(accB, bf1, 0, 1);   // slot 5
        if (jt < 15) load_slot(bf0, jt + 1, 0);
        mfma_slot(accB, bf2, 1, 0);                           // slot 6
        if (jt < 15) load_slot(bf1, jt + 1, 1);
        mfma_slot(accB, bf3, 1, 1);                           // slot 7
        epilogue_half(accA, jt, 0);
    }
    epilogue_half(accB, 15, 1);

    // ---- block-end row reduction ----
    float rout = 0.0f;
    #pragma unroll
    for (int rb = 0; rb < 4; ++rb)
        #pragma unroll
        for (int r = 0; r < 4; ++r) {
            float v = rp[rb][r];
            v += __shfl_xor(v, 1, 16);
            v += __shfl_xor(v, 2, 16);
            v += __shfl_xor(v, 4, 16);
            v += __shfl_xor(v, 8, 16);
            if (m == ((rb << 2) | r)) rout = v;
        }
    atomicAdd(&s_row[row0 + (wr << 6) + ((m >> 2) << 4) + (q << 2) + (m & 3)], rout);
}

// ---------- kernel 3: final reduce (64 blocks, 256 rows each) ----------
// diag is biased by -144; the +144 LSE un-bias cancels it exactly.
__global__ void final_kernel(const float* __restrict__ s_row, const float* __restrict__ s_col,
                             const float* __restrict__ diag, float* __restrict__ out) {
    __shared__ double red[256];
    int t = threadIdx.x;
    int i = blockIdx.x * 256 + t;
    double p = 0.5 * (double)(log2f(s_row[i]) + log2f(s_col[i])) - (double)diag[i];
    red[t] = p;
    __syncthreads();
    for (int s = 128; s > 0; s >>= 1) {
        if (t < s) red[t] += red[t + s];
        __syncthreads();
    }
    if (t == 0) atomicAdd(out, (float)(red[0] * 0.6931471805599453 / (double)NN));
}

// ---------- launch ----------
extern "C" void kernel_launch(void* const* d_in, const int* in_sizes, int n_in,
                              void* d_out, int out_size, void* d_ws, size_t ws_size,
                              hipStream_t stream) {
    const float* img = (const float*)d_in[0];
    const float* txt = (const float*)d_in[1];
    char* ws = (char*)d_ws;
    u8*    A8    = (u8*)ws;                                // 4 MB
    u8*    B8    = (u8*)(ws + 4194304);                    // 4 MB
    float* s_row = (float*)(ws + 8388608);                 // 64 KB
    float* s_col = (float*)(ws + 8388608 + 65536);         // 64 KB
    float* diag  = (float*)(ws + 8388608 + 131072);        // 64 KB
    float* out   = (float*)d_out;

    prep_kernel<<<1024, 256, 0, stream>>>(img, txt, A8, B8, s_row, out);
    gemm_lse_kernel<<<1024, 256, 0, stream>>>(A8, B8, s_row, s_col, diag);
    final_kernel<<<64, 256, 0, stream>>>(s_row, s_col, diag, out);
}